// Round 1
// baseline (1501.342 us; speedup 1.0000x reference)
//
#include <hip/hip_runtime.h>

// VQProsodyEncoder on gfx950: 13x conv1d(K=5) as implicit-GEMM f16 MFMA,
// maxpool(8), VQ via (-2*z.c + |c|^2) GEMM + argmin + gather.
// Activations: channel-last f16 [B][T+4][C] with 2-row zero halos (conv taps
// become pointer shifts -> unpredicated 16B global_load_lds staging).

typedef _Float16 f16;
typedef __attribute__((ext_vector_type(8))) _Float16 half8;
typedef __attribute__((ext_vector_type(4))) _Float16 half4;
typedef __attribute__((ext_vector_type(4))) float float4v;

__device__ __forceinline__ void async16(const void* g, void* l) {
  __builtin_amdgcn_global_load_lds(
      (const __attribute__((address_space(1))) void*)g,
      (__attribute__((address_space(3))) void*)l, 16, 0, 0);
}

// ---------------------------------------------------------------------------
// conv as implicit GEMM: Y[b,t,o] = sum_{kt,ci} W[kt][o][ci] * X[b][t+kt-2][ci]
// tile 128(M=o) x 128(N=b*t), BK=32, 4 waves, mfma_f32_16x16x32_f16.
__global__ __launch_bounds__(256) void conv_gemm(
    const f16* __restrict__ Xb,   // [B][T+4][Cinp], halo rows zeroed
    const f16* __restrict__ Wp,   // [ntap][Cout][Cinp]
    const float* __restrict__ bias,   // [Cout]
    const f16* __restrict__ Res,  // [B][T+4][Cout] or null (residual add)
    float* __restrict__ Yf,       // [B][T][Cout] or null
    f16* __restrict__ Yb,         // [B][T+4][Cout] or null
    int Cinp, int Cout, int lgT, int ntap, int tapshift, int relu)
{
  __shared__ __align__(16) f16 Als[128 * 32];
  __shared__ __align__(16) f16 Bls[128 * 32];

  const int tid  = threadIdx.x;
  const int wave = tid >> 6;
  const int lane = tid & 63;
  const int T  = 1 << lgT;
  const int n0 = blockIdx.x << 7;
  const int o0 = blockIdx.y << 7;
  const int b  = n0 >> lgT;
  const int t0 = n0 & (T - 1);

  // staging mapping: lane i -> row srow (16 rows/call), 8-elem k-group skg8
  const int srow = lane >> 2;
  const int skg8 = (lane & 3) << 3;
  const int aBase = (o0 + wave * 32 + srow) * Cinp + skg8;
  const int bBase = (b * (T + 4) + t0 + wave * 32 + srow) * Cinp + skg8;
  const int cHalf = 16 * Cinp;

  f16* ldsA = &Als[wave * 1024];
  f16* ldsB = &Bls[wave * 1024];

  float4v acc[4][4] = {};

  const int mB  = (wave & 1) * 64;
  const int nB  = (wave >> 1) * 64;
  const int r16 = lane & 15;
  const int q8  = (lane >> 4) << 3;

  for (int kt = 0; kt < ntap; ++kt) {
    const f16* gA = Wp + kt * Cout * Cinp + aBase;
    const f16* gB = Xb + bBase + (tapshift + kt) * Cinp;
#pragma unroll 1
    for (int ci = 0; ci < Cinp; ci += 32) {
      __syncthreads();                       // prev iteration's reads done
      async16(gA + ci,         ldsA);        // A rows [w*32, w*32+16)
      async16(gA + ci + cHalf, ldsA + 512);  // A rows [w*32+16, w*32+32)
      async16(gB + ci,         ldsB);
      async16(gB + ci + cHalf, ldsB + 512);
      __syncthreads();                       // drains vmcnt, staging visible
      half8 af[4], bv[4];
#pragma unroll
      for (int i = 0; i < 4; ++i)
        af[i] = *(const half8*)&Als[(mB + i * 16 + r16) * 32 + q8];
#pragma unroll
      for (int j = 0; j < 4; ++j)
        bv[j] = *(const half8*)&Bls[(nB + j * 16 + r16) * 32 + q8];
#pragma unroll
      for (int i = 0; i < 4; ++i)
#pragma unroll
        for (int j = 0; j < 4; ++j)
          acc[i][j] = __builtin_amdgcn_mfma_f32_16x16x32_f16(af[i], bv[j], acc[i][j], 0, 0, 0);
    }
  }

  // epilogue: D[row][col]: col = lane&15, row = (lane>>4)*4 + reg
  const int col = lane & 15;
  const int qr4 = (lane >> 4) << 2;
#pragma unroll
  for (int i = 0; i < 4; ++i) {
    const int o = o0 + mB + i * 16 + qr4;
    const float4v bb = *(const float4v*)&bias[o];
#pragma unroll
    for (int j = 0; j < 4; ++j) {
      const int t = t0 + nB + j * 16 + col;
      float4v v = acc[i][j] + bb;
      if (relu) {
        v.x = fmaxf(v.x, 0.f); v.y = fmaxf(v.y, 0.f);
        v.z = fmaxf(v.z, 0.f); v.w = fmaxf(v.w, 0.f);
      }
      if (Res) {
        half4 r = *(const half4*)&Res[(b * (T + 4) + t + 2) * Cout + o];
        v.x += (float)r.x; v.y += (float)r.y; v.z += (float)r.z; v.w += (float)r.w;
      }
      if (Yf) *(float4v*)&Yf[(b * T + t) * Cout + o] = v;
      if (Yb) {
        half4 h;
        h.x = (f16)v.x; h.y = (f16)v.y; h.z = (f16)v.z; h.w = (f16)v.w;
        *(half4*)&Yb[(b * (T + 4) + t + 2) * Cout + o] = h;
      }
    }
  }
}

// ---------------------------------------------------------------------------
__global__ void repack_w(const float* __restrict__ w,  // [L][O][I][5]
                         f16* __restrict__ wp,          // [L][5][O][Ip]
                         int O, int I, int Ip)
{
  const int lkt = blockIdx.y;
  const int l = lkt / 5, kt = lkt % 5;
  const float* wl = w + (size_t)l * O * I * 5;
  f16* wpl = wp + (size_t)lkt * O * Ip;
  const int n = O * Ip;
  for (int e = blockIdx.x * 256 + threadIdx.x; e < n; e += gridDim.x * 256) {
    int o = e / Ip, ip = e - o * Ip;
    float v = (ip < I) ? wl[(o * I + ip) * 5 + kt] : 0.f;
    wpl[e] = (f16)v;
  }
}

__global__ void cb_repack(const float* __restrict__ cb,  // [1024][256]
                          f16* __restrict__ wcb,          // [1024][256] = -2c
                          float* __restrict__ cnorm)      // [1024] = |c|^2
{
  int row = blockIdx.x;
  int lane = threadIdx.x;  // 64
  float4v c = *(const float4v*)&cb[(size_t)row * 256 + lane * 4];
  half4 h;
  h.x = (f16)(-2.f * c.x); h.y = (f16)(-2.f * c.y);
  h.z = (f16)(-2.f * c.z); h.w = (f16)(-2.f * c.w);
  *(half4*)&wcb[(size_t)row * 256 + lane * 4] = h;
  float s = c.x * c.x + c.y * c.y + c.z * c.z + c.w * c.w;
  for (int off = 32; off > 0; off >>= 1) s += __shfl_down(s, off);
  if (lane == 0) cnorm[row] = s;
}

__global__ void mel_to_f16(const float* __restrict__ mel,  // [32][2048][80]
                           f16* __restrict__ out)           // [32][2052][96]
{
  int idx = blockIdx.x * 256 + threadIdx.x;
  if (idx >= 32 * 2052 * 12) return;
  int c8 = idx % 12;
  int r  = idx / 12;
  int tt = r % 2052;
  int b  = r / 2052;
  int t  = tt - 2;
  bool trow = (t >= 0) && (t < 2048);
  half8 hv;
#pragma unroll
  for (int e = 0; e < 8; ++e) {
    int m = c8 * 8 + e;
    float v = (trow && m < 80) ? mel[((size_t)b * 2048 + t) * 80 + m] : 0.f;
    hv[e] = (f16)v;
  }
  *(half8*)&out[((size_t)b * 2052 + tt) * 96 + c8 * 8] = hv;
}

__global__ void maxpool8(const f16* __restrict__ X,  // [32][2052][384]
                         f16* __restrict__ Y)         // [32][260][384]
{
  int idx = blockIdx.x * 256 + threadIdx.x;
  if (idx >= 32 * 256 * 384) return;
  int c  = idx % 384;
  int r  = idx / 384;
  int tp = r % 256;
  int b  = r / 256;
  const f16* xp = &X[((size_t)b * 2052 + tp * 8 + 2) * 384 + c];
  float m = (float)xp[0];
#pragma unroll
  for (int s = 1; s < 8; ++s) m = fmaxf(m, (float)xp[(size_t)s * 384]);
  Y[((size_t)b * 260 + tp + 2) * 384 + c] = (f16)m;
}

__global__ void halo_zero(f16* a0, f16* a1, f16* b0, f16* b1, f16* zb,
                          float* accum)
{
  int bid = blockIdx.x;  // 5 bufs * 32 batches * 4 rows = 640
  if (bid == 0 && threadIdx.x == 0) { accum[0] = 0.f; accum[1] = 0.f; }
  int buf = bid >> 7;
  int r = bid & 127;
  int bb = r >> 2;
  int k = r & 3;
  f16* p; int T4, C;
  if      (buf == 0) { p = a0; T4 = 2052; C = 384; }
  else if (buf == 1) { p = a1; T4 = 2052; C = 384; }
  else if (buf == 2) { p = b0; T4 = 260;  C = 384; }
  else if (buf == 3) { p = b1; T4 = 260;  C = 384; }
  else               { p = zb; T4 = 260;  C = 256; }
  int tt = (k < 2) ? k : (T4 - 4 + k);
  f16* rowp = p + ((size_t)bb * T4 + tt) * C;
  for (int c = threadIdx.x; c < C; c += 256) rowp[c] = (f16)0.f;
}

__global__ void argmin_rows(const float* __restrict__ S,  // [8192][1024]
                            int* __restrict__ outIdx)
{
  int row = blockIdx.x * 4 + (threadIdx.x >> 6);
  int lane = threadIdx.x & 63;
  const float* sr = S + (size_t)row * 1024;
  float bv = 3.4e38f;
  int bi = 0;
#pragma unroll
  for (int g = 0; g < 4; ++g) {
    float4v v = *(const float4v*)&sr[g * 256 + lane * 4];
#pragma unroll
    for (int e = 0; e < 4; ++e) {
      float f = v[e];
      int id = g * 256 + lane * 4 + e;
      if (f < bv || (f == bv && id < bi)) { bv = f; bi = id; }
    }
  }
  for (int off = 32; off > 0; off >>= 1) {
    float ov = __shfl_down(bv, off);
    int oi = __shfl_down(bi, off);
    if (ov < bv || (ov == bv && oi < bi)) { bv = ov; bi = oi; }
  }
  if (lane == 0) outIdx[row] = bi;
}

__global__ void vq_gather(const float* __restrict__ zf,   // [8192][256]
                          const float* __restrict__ cb,   // [1024][256]
                          const int* __restrict__ idx,
                          float* __restrict__ zq,          // [8192][256]
                          float* __restrict__ accum)
{
  int row = blockIdx.x;
  int lane = threadIdx.x;  // 64
  int j = idx[row];
  float4v z = *(const float4v*)&zf[(size_t)row * 256 + lane * 4];
  float4v q = *(const float4v*)&cb[(size_t)j * 256 + lane * 4];
  *(float4v*)&zq[(size_t)row * 256 + lane * 4] = q;
  float4v d = z - q;
  float s = d.x * d.x + d.y * d.y + d.z * d.z + d.w * d.w;
  for (int off = 32; off > 0; off >>= 1) s += __shfl_down(s, off);
  if (lane == 0) atomicAdd(accum, s);
}

__global__ void finalize_loss(const float* __restrict__ accum,
                              float* __restrict__ out2)
{
  float c = accum[0] * (1.0f / 2097152.0f);  // mean over 32*256*256
  out2[0] = c;   // commit_loss
  out2[1] = c;   // vq_loss (== commit_loss numerically)
}

// ---------------------------------------------------------------------------
extern "C" void kernel_launch(void* const* d_in, const int* in_sizes, int n_in,
                              void* d_out, int out_size, void* d_ws, size_t ws_size,
                              hipStream_t stream)
{
  (void)in_sizes; (void)n_in; (void)out_size;
  const float* mel    = (const float*)d_in[0];
  const float* w_pre  = (const float*)d_in[1];
  const float* b_pre  = (const float*)d_in[2];
  const float* w_b1   = (const float*)d_in[3];
  const float* b_b1   = (const float*)d_in[4];
  const float* w_b2   = (const float*)d_in[5];
  const float* b_b2   = (const float*)d_in[6];
  const float* w_post = (const float*)d_in[7];
  const float* b_post = (const float*)d_in[8];
  const float* cbk    = (const float*)d_in[9];
  float* out = (float*)d_out;

  size_t off = 0;
  auto carve = [&](size_t bytes) -> char* {
    char* p = (char*)d_ws + off;
    off += (bytes + 255) & ~(size_t)255;
    return p;
  };
  f16*   wpPre  = (f16*)carve((size_t)5 * 384 * 96 * 2);
  f16*   wpB1   = (f16*)carve((size_t)6 * 5 * 384 * 384 * 2);
  f16*   wpB2   = (f16*)carve((size_t)6 * 5 * 384 * 384 * 2);
  f16*   wpPost = (f16*)carve((size_t)5 * 256 * 384 * 2);
  f16*   wpCb   = (f16*)carve((size_t)1024 * 256 * 2);
  float* cnorm  = (float*)carve(1024 * 4);
  float* accum  = (float*)carve(256);
  f16*   xmel   = (f16*)carve((size_t)32 * 2052 * 96 * 2);
  f16*   xa0    = (f16*)carve((size_t)32 * 2052 * 384 * 2);
  f16*   xa1    = (f16*)carve((size_t)32 * 2052 * 384 * 2);
  f16*   xb0    = (f16*)carve((size_t)32 * 260 * 384 * 2);
  f16*   xb1    = (f16*)carve((size_t)32 * 260 * 384 * 2);
  f16*   zeb    = (f16*)carve((size_t)32 * 260 * 256 * 2);
  float* zf     = (float*)carve((size_t)32 * 256 * 256 * 4);
  float* scores = (float*)carve((size_t)8192 * 1024 * 4);
  int*   idxb   = (int*)carve((size_t)8192 * 4);
  if (off > ws_size) return;  // ~184 MB needed

  halo_zero<<<640, 256, 0, stream>>>(xa0, xa1, xb0, xb1, zeb, accum);
  repack_w<<<dim3(144, 5),  256, 0, stream>>>(w_pre,  wpPre,  384, 80,  96);
  repack_w<<<dim3(576, 30), 256, 0, stream>>>(w_b1,   wpB1,   384, 384, 384);
  repack_w<<<dim3(576, 30), 256, 0, stream>>>(w_b2,   wpB2,   384, 384, 384);
  repack_w<<<dim3(384, 5),  256, 0, stream>>>(w_post, wpPost, 256, 384, 384);
  cb_repack<<<1024, 64, 0, stream>>>(cbk, wpCb, cnorm);
  mel_to_f16<<<3078, 256, 0, stream>>>(mel, xmel);

  auto conv = [&](const f16* X, const f16* W, const float* bia, const f16* R,
                  float* YF, f16* YB, int Cinp, int Cout, int lgT, int ntap,
                  int tapshift, int relu) {
    dim3 g((32 << lgT) >> 7, Cout >> 7);
    conv_gemm<<<g, 256, 0, stream>>>(X, W, bia, R, YF, YB, Cinp, Cout, lgT,
                                     ntap, tapshift, relu);
  };

  // pre-conv: relu(conv(mel))
  conv(xmel, wpPre, b_pre, nullptr, nullptr, xa0, 96, 384, 11, 5, 0, 1);
  // stack 1 @ T=2048
  for (int i = 0; i < 6; ++i) {
    f16* in = (i & 1) ? xa1 : xa0;
    f16* o_ = (i & 1) ? xa0 : xa1;
    conv(in, wpB1 + (size_t)i * 5 * 384 * 384, b_b1 + i * 384, in,
         nullptr, o_, 384, 384, 11, 5, 0, 1);
  }
  maxpool8<<<12288, 256, 0, stream>>>(xa0, xb0);
  // stack 2 @ T=256
  for (int i = 0; i < 6; ++i) {
    f16* in = (i & 1) ? xb1 : xb0;
    f16* o_ = (i & 1) ? xb0 : xb1;
    conv(in, wpB2 + (size_t)i * 5 * 384 * 384, b_b2 + i * 384, in,
         nullptr, o_, 384, 384, 8, 5, 0, 1);
  }
  // post-conv: ze (f32 for loss, f16+halo for VQ scores)
  conv(xb0, wpPost, b_post, nullptr, zf, zeb, 384, 256, 8, 5, 0, 0);
  // VQ scores: |c|^2 - 2 z.c  as a 1-tap "conv" (tapshift=2 = no shift)
  conv(zeb, wpCb, cnorm, nullptr, scores, nullptr, 256, 1024, 8, 1, 2, 0);

  argmin_rows<<<2048, 256, 0, stream>>>(scores, idxb);
  vq_gather<<<8192, 64, 0, stream>>>(zf, cbk, idxb, out, accum);
  finalize_loss<<<1, 1, 0, stream>>>(accum, out + 2097152);
}

// Round 2
// 1209.469 us; speedup vs baseline: 1.2413x; 1.2413x over previous
//
#include <hip/hip_runtime.h>

// VQProsodyEncoder on gfx950: 13x conv1d(K=5) as implicit-GEMM f16 MFMA,
// maxpool(8), VQ via (-2*z.c + |c|^2) GEMM + argmin + gather.
// Activations: channel-last f16 [B][T+4][C] with 2-row zero halos.
// R2: tap-reuse K-loop — per ci-chunk stage A[NTAP][128][32] + B[144][32]
// once, 80 MFMA per barrier pair (was 16), X staged once per o-tile (was 5x).

typedef _Float16 f16;
typedef __attribute__((ext_vector_type(8))) _Float16 half8;
typedef __attribute__((ext_vector_type(4))) _Float16 half4;
typedef __attribute__((ext_vector_type(4))) float float4v;

__device__ __forceinline__ void async16(const void* g, void* l) {
  __builtin_amdgcn_global_load_lds(
      (const __attribute__((address_space(1))) void*)g,
      (__attribute__((address_space(3))) void*)l, 16, 0, 0);
}

// ---------------------------------------------------------------------------
// conv as implicit GEMM: Y[b,t,o] = sum_{kt,ci} W[kt][o][ci] * X[b][t+kt-2][ci]
// tile 128(M=o) x 128(N=b*t), BK=32, 4 waves 64x64, mfma_f32_16x16x32_f16.
template <int NTAP>
__global__ __launch_bounds__(256, 3) void conv_gemm(
    const f16* __restrict__ Xb,   // [B][T+4][Cinp], halo rows zeroed
    const f16* __restrict__ Wp,   // [NTAP][Cout][Cinp]
    const float* __restrict__ bias,  // [Cout]
    const f16* __restrict__ Res,  // [B][T+4][Cout] or null (residual add)
    float* __restrict__ Yf,       // [B][T][Cout] or null
    f16* __restrict__ Yb,         // [B][T+4][Cout] or null
    int Cinp, int Cout, int lgT, int tapshift, int relu)
{
  __shared__ __align__(16) f16 Als[5 * 128 * 32];  // [tap][128 o][32 ci]
  __shared__ __align__(16) f16 Bls[144 * 32];      // [144 t][32 ci]

  const int tid  = threadIdx.x;
  const int wave = tid >> 6;
  const int lane = tid & 63;
  const int T  = 1 << lgT;
  const int n0 = blockIdx.x << 7;
  const int o0 = blockIdx.y << 7;
  const int b  = n0 >> lgT;
  const int t0 = n0 & (T - 1);

  const int lane4 = lane >> 2;        // row within a 16-row wave-round
  const int lk    = (lane & 3) << 3;  // f16 k-offset within 32-chunk

  const f16* gA0 = Wp + (o0 * Cinp) + lk;
  const f16* gB0 = Xb + (size_t)(b * (T + 4) + t0) * Cinp + lk;

  float4v acc[4][4] = {};

  const int mB  = (wave & 1) * 64;
  const int nB  = (wave >> 1) * 64;
  const int r16 = lane & 15;
  const int q8  = (lane >> 4) << 3;

#pragma unroll 1
  for (int ci = 0; ci < Cinp; ci += 32) {
    __syncthreads();  // previous iteration's LDS reads complete
    // stage A: NTAP*8 wave-rounds of 16 rows x 32 f16 (1 KB per wave-round)
#pragma unroll
    for (int c = wave; c < NTAP * 8; c += 4) {
      const int tap  = c >> 3;
      const int orow = ((c & 7) << 4) + lane4;
      async16(gA0 + (size_t)(tap * Cout + orow) * Cinp + ci,
              &Als[c * 512 + lane * 8]);
    }
    // stage B: 9 wave-rounds = 144 t-rows (rows >=132 junk, never read)
#pragma unroll
    for (int r = wave; r < 9; r += 4) {
      async16(gB0 + (size_t)(r * 16 + lane4) * Cinp + ci,
              &Bls[r * 512 + lane * 8]);
    }
    __syncthreads();  // drains vmcnt: staging visible

#pragma unroll
    for (int kt = 0; kt < NTAP; ++kt) {
      half8 af[4], bv[4];
#pragma unroll
      for (int i = 0; i < 4; ++i)
        af[i] = *(const half8*)&Als[(kt * 128 + mB + i * 16 + r16) * 32 + q8];
#pragma unroll
      for (int j = 0; j < 4; ++j)
        bv[j] = *(const half8*)&Bls[(nB + j * 16 + r16 + tapshift + kt) * 32 + q8];
#pragma unroll
      for (int i = 0; i < 4; ++i)
#pragma unroll
        for (int j = 0; j < 4; ++j)
          acc[i][j] = __builtin_amdgcn_mfma_f32_16x16x32_f16(af[i], bv[j], acc[i][j], 0, 0, 0);
    }
  }

  // epilogue: D[row][col]: col = lane&15, row = (lane>>4)*4 + reg
  const int col = lane & 15;
  const int qr4 = (lane >> 4) << 2;
#pragma unroll
  for (int i = 0; i < 4; ++i) {
    const int o = o0 + mB + i * 16 + qr4;
    const float4v bb = *(const float4v*)&bias[o];
#pragma unroll
    for (int j = 0; j < 4; ++j) {
      const int t = t0 + nB + j * 16 + col;
      float4v v = acc[i][j] + bb;
      if (relu) {
        v.x = fmaxf(v.x, 0.f); v.y = fmaxf(v.y, 0.f);
        v.z = fmaxf(v.z, 0.f); v.w = fmaxf(v.w, 0.f);
      }
      if (Res) {
        half4 r = *(const half4*)&Res[(size_t)(b * (T + 4) + t + 2) * Cout + o];
        v.x += (float)r.x; v.y += (float)r.y; v.z += (float)r.z; v.w += (float)r.w;
      }
      if (Yf) *(float4v*)&Yf[(size_t)(b * T + t) * Cout + o] = v;
      if (Yb) {
        half4 h;
        h.x = (f16)v.x; h.y = (f16)v.y; h.z = (f16)v.z; h.w = (f16)v.w;
        *(half4*)&Yb[(size_t)(b * (T + 4) + t + 2) * Cout + o] = h;
      }
    }
  }
}

// ---------------------------------------------------------------------------
__global__ void repack_w(const float* __restrict__ w,  // [L][O][I][5]
                         f16* __restrict__ wp,          // [L][5][O][Ip]
                         int O, int I, int Ip)
{
  const int lkt = blockIdx.y;
  const int l = lkt / 5, kt = lkt % 5;
  const float* wl = w + (size_t)l * O * I * 5;
  f16* wpl = wp + (size_t)lkt * O * Ip;
  const int n = O * Ip;
  for (int e = blockIdx.x * 256 + threadIdx.x; e < n; e += gridDim.x * 256) {
    int o = e / Ip, ip = e - o * Ip;
    float v = (ip < I) ? wl[(o * I + ip) * 5 + kt] : 0.f;
    wpl[e] = (f16)v;
  }
}

__global__ void cb_repack(const float* __restrict__ cb,  // [1024][256]
                          f16* __restrict__ wcb,          // [1024][256] = -2c
                          float* __restrict__ cnorm)      // [1024] = |c|^2
{
  int row = blockIdx.x;
  int lane = threadIdx.x;  // 64
  float4v c = *(const float4v*)&cb[(size_t)row * 256 + lane * 4];
  half4 h;
  h.x = (f16)(-2.f * c.x); h.y = (f16)(-2.f * c.y);
  h.z = (f16)(-2.f * c.z); h.w = (f16)(-2.f * c.w);
  *(half4*)&wcb[(size_t)row * 256 + lane * 4] = h;
  float s = c.x * c.x + c.y * c.y + c.z * c.z + c.w * c.w;
  for (int off = 32; off > 0; off >>= 1) s += __shfl_down(s, off);
  if (lane == 0) cnorm[row] = s;
}

__global__ void mel_to_f16(const float* __restrict__ mel,  // [32][2048][80]
                           f16* __restrict__ out)           // [32][2052][96]
{
  int idx = blockIdx.x * 256 + threadIdx.x;
  if (idx >= 32 * 2052 * 12) return;
  int c8 = idx % 12;
  int r  = idx / 12;
  int tt = r % 2052;
  int b  = r / 2052;
  int t  = tt - 2;
  bool trow = (t >= 0) && (t < 2048);
  half8 hv;
#pragma unroll
  for (int e = 0; e < 8; ++e) {
    int m = c8 * 8 + e;
    float v = (trow && m < 80) ? mel[((size_t)b * 2048 + t) * 80 + m] : 0.f;
    hv[e] = (f16)v;
  }
  *(half8*)&out[((size_t)b * 2052 + tt) * 96 + c8 * 8] = hv;
}

__global__ void maxpool8(const f16* __restrict__ X,  // [32][2052][384]
                         f16* __restrict__ Y)         // [32][260][384]
{
  int idx = blockIdx.x * 256 + threadIdx.x;
  if (idx >= 32 * 256 * 384) return;
  int c  = idx % 384;
  int r  = idx / 384;
  int tp = r % 256;
  int b  = r / 256;
  const f16* xp = &X[((size_t)b * 2052 + tp * 8 + 2) * 384 + c];
  float m = (float)xp[0];
#pragma unroll
  for (int s = 1; s < 8; ++s) m = fmaxf(m, (float)xp[(size_t)s * 384]);
  Y[((size_t)b * 260 + tp + 2) * 384 + c] = (f16)m;
}

__global__ void halo_zero(f16* a0, f16* a1, f16* b0, f16* b1, f16* zb,
                          float* accum)
{
  int bid = blockIdx.x;  // 5 bufs * 32 batches * 4 rows = 640
  if (bid == 0 && threadIdx.x == 0) { accum[0] = 0.f; accum[1] = 0.f; }
  int buf = bid >> 7;
  int r = bid & 127;
  int bb = r >> 2;
  int k = r & 3;
  f16* p; int T4, C;
  if      (buf == 0) { p = a0; T4 = 2052; C = 384; }
  else if (buf == 1) { p = a1; T4 = 2052; C = 384; }
  else if (buf == 2) { p = b0; T4 = 260;  C = 384; }
  else if (buf == 3) { p = b1; T4 = 260;  C = 384; }
  else               { p = zb; T4 = 260;  C = 256; }
  int tt = (k < 2) ? k : (T4 - 4 + k);
  f16* rowp = p + ((size_t)bb * T4 + tt) * C;
  for (int c = threadIdx.x; c < C; c += 256) rowp[c] = (f16)0.f;
}

__global__ void argmin_rows(const float* __restrict__ S,  // [8192][1024]
                            int* __restrict__ outIdx)
{
  int row = blockIdx.x * 4 + (threadIdx.x >> 6);
  int lane = threadIdx.x & 63;
  const float* sr = S + (size_t)row * 1024;
  float bv = 3.4e38f;
  int bi = 0;
#pragma unroll
  for (int g = 0; g < 4; ++g) {
    float4v v = *(const float4v*)&sr[g * 256 + lane * 4];
#pragma unroll
    for (int e = 0; e < 4; ++e) {
      float f = v[e];
      int id = g * 256 + lane * 4 + e;
      if (f < bv || (f == bv && id < bi)) { bv = f; bi = id; }
    }
  }
  for (int off = 32; off > 0; off >>= 1) {
    float ov = __shfl_down(bv, off);
    int oi = __shfl_down(bi, off);
    if (ov < bv || (ov == bv && oi < bi)) { bv = ov; bi = oi; }
  }
  if (lane == 0) outIdx[row] = bi;
}

__global__ void vq_gather(const float* __restrict__ zf,   // [8192][256]
                          const float* __restrict__ cb,   // [1024][256]
                          const int* __restrict__ idx,
                          float* __restrict__ zq,          // [8192][256]
                          float* __restrict__ accum)
{
  int row = blockIdx.x;
  int lane = threadIdx.x;  // 64
  int j = idx[row];
  float4v z = *(const float4v*)&zf[(size_t)row * 256 + lane * 4];
  float4v q = *(const float4v*)&cb[(size_t)j * 256 + lane * 4];
  *(float4v*)&zq[(size_t)row * 256 + lane * 4] = q;
  float4v d = z - q;
  float s = d.x * d.x + d.y * d.y + d.z * d.z + d.w * d.w;
  for (int off = 32; off > 0; off >>= 1) s += __shfl_down(s, off);
  if (lane == 0) atomicAdd(accum, s);
}

__global__ void finalize_loss(const float* __restrict__ accum,
                              float* __restrict__ out2)
{
  float c = accum[0] * (1.0f / 2097152.0f);  // mean over 32*256*256
  out2[0] = c;   // commit_loss
  out2[1] = c;   // vq_loss (== commit_loss numerically)
}

// ---------------------------------------------------------------------------
extern "C" void kernel_launch(void* const* d_in, const int* in_sizes, int n_in,
                              void* d_out, int out_size, void* d_ws, size_t ws_size,
                              hipStream_t stream)
{
  (void)in_sizes; (void)n_in; (void)out_size;
  const float* mel    = (const float*)d_in[0];
  const float* w_pre  = (const float*)d_in[1];
  const float* b_pre  = (const float*)d_in[2];
  const float* w_b1   = (const float*)d_in[3];
  const float* b_b1   = (const float*)d_in[4];
  const float* w_b2   = (const float*)d_in[5];
  const float* b_b2   = (const float*)d_in[6];
  const float* w_post = (const float*)d_in[7];
  const float* b_post = (const float*)d_in[8];
  const float* cbk    = (const float*)d_in[9];
  float* out = (float*)d_out;

  size_t off = 0;
  auto carve = [&](size_t bytes) -> char* {
    char* p = (char*)d_ws + off;
    off += (bytes + 255) & ~(size_t)255;
    return p;
  };
  f16*   wpPre  = (f16*)carve((size_t)5 * 384 * 96 * 2);
  f16*   wpB1   = (f16*)carve((size_t)6 * 5 * 384 * 384 * 2);
  f16*   wpB2   = (f16*)carve((size_t)6 * 5 * 384 * 384 * 2);
  f16*   wpPost = (f16*)carve((size_t)5 * 256 * 384 * 2);
  f16*   wpCb   = (f16*)carve((size_t)1024 * 256 * 2);
  float* cnorm  = (float*)carve(1024 * 4);
  float* accum  = (float*)carve(256);
  f16*   xmel   = (f16*)carve((size_t)32 * 2052 * 96 * 2);
  f16*   xa0    = (f16*)carve((size_t)32 * 2052 * 384 * 2);
  f16*   xa1    = (f16*)carve((size_t)32 * 2052 * 384 * 2);
  f16*   xb0    = (f16*)carve((size_t)32 * 260 * 384 * 2);
  f16*   xb1    = (f16*)carve((size_t)32 * 260 * 384 * 2);
  f16*   zeb    = (f16*)carve((size_t)32 * 260 * 256 * 2);
  float* zf     = (float*)carve((size_t)32 * 256 * 256 * 4);
  float* scores = (float*)carve((size_t)8192 * 1024 * 4);
  int*   idxb   = (int*)carve((size_t)8192 * 4);
  carve(65536);  // guard: B staging over-reads up to ~12 rows past last buffer
  if (off > ws_size) return;  // ~184 MB needed

  halo_zero<<<640, 256, 0, stream>>>(xa0, xa1, xb0, xb1, zeb, accum);
  repack_w<<<dim3(144, 5),  256, 0, stream>>>(w_pre,  wpPre,  384, 80,  96);
  repack_w<<<dim3(576, 30), 256, 0, stream>>>(w_b1,   wpB1,   384, 384, 384);
  repack_w<<<dim3(576, 30), 256, 0, stream>>>(w_b2,   wpB2,   384, 384, 384);
  repack_w<<<dim3(384, 5),  256, 0, stream>>>(w_post, wpPost, 256, 384, 384);
  cb_repack<<<1024, 64, 0, stream>>>(cbk, wpCb, cnorm);
  mel_to_f16<<<3078, 256, 0, stream>>>(mel, xmel);

  auto conv5 = [&](const f16* X, const f16* W, const float* bia, const f16* R,
                   float* YF, f16* YB, int Cinp, int Cout, int lgT, int relu) {
    dim3 g((32 << lgT) >> 7, Cout >> 7);
    conv_gemm<5><<<g, 256, 0, stream>>>(X, W, bia, R, YF, YB, Cinp, Cout, lgT,
                                        0, relu);
  };

  // pre-conv: relu(conv(mel))
  conv5(xmel, wpPre, b_pre, nullptr, nullptr, xa0, 96, 384, 11, 1);
  // stack 1 @ T=2048
  for (int i = 0; i < 6; ++i) {
    f16* in = (i & 1) ? xa1 : xa0;
    f16* o_ = (i & 1) ? xa0 : xa1;
    conv5(in, wpB1 + (size_t)i * 5 * 384 * 384, b_b1 + i * 384, in,
          nullptr, o_, 384, 384, 11, 1);
  }
  maxpool8<<<12288, 256, 0, stream>>>(xa0, xb0);
  // stack 2 @ T=256
  for (int i = 0; i < 6; ++i) {
    f16* in = (i & 1) ? xb1 : xb0;
    f16* o_ = (i & 1) ? xb0 : xb1;
    conv5(in, wpB2 + (size_t)i * 5 * 384 * 384, b_b2 + i * 384, in,
          nullptr, o_, 384, 384, 8, 1);
  }
  // post-conv: ze (f32 for loss, f16+halo for VQ scores)
  conv5(xb0, wpPost, b_post, nullptr, zf, zeb, 384, 256, 8, 0);
  // VQ scores: |c|^2 - 2 z.c  as a 1-tap "conv" (tapshift=2 = centered)
  {
    dim3 g((32 * 256) >> 7, 1024 >> 7);
    conv_gemm<1><<<g, 256, 0, stream>>>(zeb, wpCb, cnorm, nullptr, scores,
                                        nullptr, 256, 1024, 8, 2, 0);
  }

  argmin_rows<<<2048, 256, 0, stream>>>(scores, idxb);
  vq_gather<<<8192, 64, 0, stream>>>(zf, cbk, idxb, out, accum);
  finalize_loss<<<1, 1, 0, stream>>>(accum, out + 2097152);
}